// Round 8
// baseline (490.372 us; speedup 1.0000x reference)
//
#include <hip/hip_runtime.h>
#include <math.h>
#include <stdint.h>

#define B_ 8
#define T_ 2048
#define D_ 1024
#define H_ 1365
#define HPAD 1536
#define NTOK (B_*T_)
#define NSAMP 5
#define NRHO 5

typedef float  f32x4  __attribute__((ext_vector_type(4)));
typedef __bf16 bf16x8 __attribute__((ext_vector_type(8)));

// ---- ws layout (bytes) ----
#define WS_SCORES 0                              // f64 [16384]
#define WS_CNT    (WS_SCORES + NTOK*8)           // int [5*8*2048]
#define WS_PREDW  (WS_CNT + NRHO*B_*T_*4)        // f64 [5][8][1024]
#define WS_FULLW  (WS_PREDW + NRHO*B_*D_*8)      // f64 [8][1024]
#define WS_SUMEFF (WS_FULLW + B_*D_*8)           // f64 [5][8]
#define WS_SUMATT (WS_SUMEFF + NRHO*B_*8)        // f64 [8]
#define WS_SUMG   (WS_SUMATT + B_*8)             // f64 [5][8]
#define WS_LR     (WS_SUMG + NRHO*B_*8)          // f64 [5]
#define WS_ZERO_BYTES (WS_LR + NRHO*8)
#define WS_STATS  WS_ZERO_BYTES                  // float2 [16384] (fallback path)
#define WS_W1THI  (WS_STATS + NTOK*8)            // ushort [1536][1024]
#define WS_W1TLO  (WS_W1THI + (size_t)HPAD*D_*2) // ushort [1536][1024]
#define WS_AHI    (WS_W1TLO + (size_t)HPAD*D_*2) // ushort [16384][1024]
#define WS_ALO    (WS_AHI + (size_t)NTOK*D_*2)   // ushort [16384][1024]
#define WS_FULL_END (WS_ALO + (size_t)NTOK*D_*2)

// ---- out layout (f32 elements) ----
#define OUT_G      0
#define OUT_GSW    16384
#define OUT_RECON  98304
#define OUT_LOSS   98305
#define OUT_RHOEFF 98310

__device__ inline unsigned short f2bf(float x) {   // RNE f32 -> bf16 bits
    uint32_t u = __float_as_uint(x);
    return (unsigned short)((u + 0x7FFFu + ((u >> 16) & 1u)) >> 16);
}

// ============================================================
// Prep: W1 [1024][1365] -> W1T hi/lo bf16 [1536][1024] (k-contiguous, zero-padded)
// ============================================================
__launch_bounds__(256)
__global__ void k_w1t(const float* __restrict__ W1, unsigned short* __restrict__ hi,
                      unsigned short* __restrict__ lo)
{
    __shared__ float tile[32][33];
    const int tid = threadIdx.x;
    const int bk = blockIdx.x & 31;
    const int bh = blockIdx.x >> 5;
    const int k0 = bk * 32, h0 = bh * 32;
    const int a = tid & 31, b = tid >> 5;
    #pragma unroll
    for (int i = 0; i < 4; ++i) {
        int k = k0 + b + i * 8;
        int h = h0 + a;
        tile[b + i*8][a] = (h < H_) ? W1[(size_t)k * H_ + h] : 0.0f;
    }
    __syncthreads();
    #pragma unroll
    for (int i = 0; i < 4; ++i) {
        int hrow = h0 + b + i * 8;
        int kcol = k0 + a;
        float v = tile[a][b + i*8];
        unsigned short hb = f2bf(v);
        float hf = __uint_as_float((uint32_t)hb << 16);
        unsigned short lb = f2bf(v - hf);
        size_t dst = (size_t)hrow * D_ + kcol;
        hi[dst] = hb; lo[dst] = lb;
    }
}

// ============================================================
// Prep: fused LN stats (f64) + f32 transform + bf16 hi/lo split -> Ahi/Alo
// ============================================================
__launch_bounds__(256)
__global__ void k_asplit(const float* __restrict__ emb, const float* __restrict__ attn,
                         const float* __restrict__ ln_g, const float* __restrict__ ln_b,
                         unsigned short* __restrict__ ahi, unsigned short* __restrict__ alo)
{
    const int tid = threadIdx.x, l = tid & 63, w = tid >> 6;
    const int t0 = blockIdx.x * 64;
    for (int tk = w; tk < 64; tk += 4) {
        const int tg = t0 + tk;
        const float av = attn[tg];
        const float* row = emb + (size_t)tg * D_;
        float rv[16];
        double s1 = 0.0, s2 = 0.0;
        #pragma unroll
        for (int i = 0; i < 16; ++i) {
            rv[i] = row[i*64 + l];
            double x = (double)rv[i] * (double)av;
            s1 += x; s2 += x * x;
        }
        for (int m = 32; m; m >>= 1) { s1 += __shfl_xor(s1, m); s2 += __shfl_xor(s2, m); }
        double mean = s1 / (double)D_;
        double var  = s2 / (double)D_ - mean * mean;
        double inv  = 1.0 / sqrt(var + 1e-5);
        float sc  = (float)((double)av * inv);
        float nsh = -(float)(mean * inv);
        #pragma unroll
        for (int i = 0; i < 16; ++i) {
            int k = i * 64 + l;
            float t  = fmaf(rv[i], sc, nsh);
            float xn = fmaf(t, ln_g[k], ln_b[k]);
            unsigned short hb = f2bf(xn);
            float hf = __uint_as_float((uint32_t)hb << 16);
            size_t dst = (size_t)tg * D_ + k;
            ahi[dst] = hb;
            alo[dst] = f2bf(xn - hf);
        }
    }
}

// (fallback path prep: per-token stats only)
__launch_bounds__(256)
__global__ void k_stats(const float* __restrict__ emb, const float* __restrict__ attn,
                        float2* __restrict__ stats)
{
    const int tid = threadIdx.x, l = tid & 63, w = tid >> 6;
    const int t0 = blockIdx.x * 64;
    for (int tk = w; tk < 64; tk += 4) {
        const int tg = t0 + tk;
        const float av = attn[tg];
        const float* row = emb + (size_t)tg * D_;
        double s1 = 0.0, s2 = 0.0;
        #pragma unroll
        for (int i = 0; i < D_/64; ++i) {
            double x = (double)row[i*64 + l] * (double)av;
            s1 += x; s2 += x * x;
        }
        for (int m = 32; m; m >>= 1) { s1 += __shfl_xor(s1, m); s2 += __shfl_xor(s2, m); }
        if (l == 0) {
            double mean = s1 / (double)D_;
            double var  = s2 / (double)D_ - mean * mean;
            double inv  = 1.0 / sqrt(var + 1e-5);
            stats[tg] = make_float2((float)((double)av * inv), (float)(mean * inv));
        }
    }
}

// ============================================================
// Kernel A: 3-term split GEMM, 2 blocks/CU for cross-block pipe overlap
//
// R8 change (R7 post-mortem: compiler sinks reg-prefetch ds_reads to the
// barrier -> intra-block SW pipelining defeated (VGPR=120 not ~200); AND
// __launch_bounds__(512,2) = 2 waves/EU = 1 block/CU all along): get TWO
// independent barrier domains per CU instead. Block A's MFMA burst overlaps
// block B's LDS/staging phase (m114: pipes co-schedule across waves).
//
// BM=128, BN=128, BK=32, 256 thr (4 waves 2x2, 64x64/wave, 4x4 16x16x32
// frags -> identical per-wave math to R3). Grid 1536 = 128 M x 12 N.
// LDS: double-buffer 2 x 32KB (Ahi 8K|Alo 8K|Bhi 8K|Blo 8K) = 64KB
// -> 2 blocks/CU by LDS (128<=160KB); __launch_bounds__(256,2): k=2x4/4=2.
// Per step t: issue 8 gll16 for t+1 -> buf t^1; read 16 frags (buf t);
// 48 MFMA; vmcnt(0) (drain covered by co-resident block); barrier.
// Buffer hazard: DMA(t)->buf (t+1)&1, last read in step t-1, consumed
// before the end-of-(t-1) barrier -> safe. Staging swizzle unchanged
// (inverse-swizzled source + swizzled ds_read, slot ^= (row>>1)&3): the
// swizzle identity needs only row mod 16 and 16-row-aligned bases, both
// preserved -> 0 bank conflicts.
// XCD swizzle mm-major (R3's FETCH-minimal topology); consecutive
// same-XCD blocks share an A-panel -> co-resident pairs hit L2 on A.
// ============================================================
#define BUF2_U 16384         // ushorts per buffer (Ahi 4K | Alo 4K | Bhi 4K | Blo 4K)
#define KSTEPS 32

__device__ __forceinline__ void gll16(const unsigned short* g, unsigned short* l)
{
    __builtin_amdgcn_global_load_lds((const __attribute__((address_space(1))) void*)g,
                                     (__attribute__((address_space(3))) void*)l, 16, 0, 0);
}

__launch_bounds__(256, 2)
__global__ void k_scores8(const unsigned short* __restrict__ ahi,
                          const unsigned short* __restrict__ alo,
                          const unsigned short* __restrict__ w1thi,
                          const unsigned short* __restrict__ w1tlo,
                          const float* __restrict__ b1, const float* __restrict__ W2,
                          double* __restrict__ scores)
{
    __shared__ __align__(16) unsigned short smem[2*BUF2_U];   // 64 KiB

    const int tid = threadIdx.x;
    const int blk = blockIdx.x;
    // XCD-aware swizzle: 1536 blocks, 8 XCDs, 192/XCD; hh fastest within chunk
    const int lin = (blk & 7) * 192 + (blk >> 3);
    const int mm = lin / 12, hh = lin - mm * 12;
    const int t0 = mm * 128;
    const int h0 = hh * 128;

    const int l  = tid & 63, w = tid >> 6;         // w in 0..3
    const int wr = w >> 1, wcn = w & 1;            // 2x2 wave grid
    const int lm = l & 15, lq = l >> 4;

    // ---- staging: per-lane global src (inverse-swizzled), wave-uniform LDS dst
    const int lrow  = l >> 2;                      // 0..15 within 16-row chunk
    const int lslot = (l & 3) ^ ((l >> 3) & 3);    // logical 16B slot for phys slot l&3
    const unsigned short* sA_hi = ahi   + (size_t)(t0 + w*32 + lrow) * D_ + lslot*8;
    const unsigned short* sA_lo = alo   + (size_t)(t0 + w*32 + lrow) * D_ + lslot*8;
    const unsigned short* sB_hi = w1thi + (size_t)(h0 + w*32 + lrow) * D_ + lslot*8;
    const unsigned short* sB_lo = w1tlo + (size_t)(h0 + w*32 + lrow) * D_ + lslot*8;
    const int dA = w * 1024;                       // wave w covers 32 rows = 1024 ushorts

    // ---- fragment read offsets (swizzled): phys_slot = lq ^ ((row>>1)&3)
    const int sw8 = (lq ^ ((lm >> 1) & 3)) * 8;
    int offA[4], offB[4];
    #pragma unroll
    for (int r = 0; r < 4; ++r) offA[r] = (wr*64 + r*16 + lm)*32 + sw8;
    #pragma unroll
    for (int c = 0; c < 4; ++c) offB[c] = 8192 + (wcn*64 + c*16 + lm)*32 + sw8;

    f32x4 acc[4][4];
    #pragma unroll
    for (int r = 0; r < 4; ++r)
        #pragma unroll
        for (int c = 0; c < 4; ++c) acc[r][c] = (f32x4){0.f, 0.f, 0.f, 0.f};

    // ---- prologue: stage buf0 (step 0)
    gll16(sA_hi,          &smem[dA]);
    gll16(sA_hi + 16*D_,  &smem[dA + 512]);
    gll16(sA_lo,          &smem[4096 + dA]);
    gll16(sA_lo + 16*D_,  &smem[4096 + dA + 512]);
    gll16(sB_hi,          &smem[8192 + dA]);
    gll16(sB_hi + 16*D_,  &smem[8192 + dA + 512]);
    gll16(sB_lo,          &smem[12288 + dA]);
    gll16(sB_lo + 16*D_,  &smem[12288 + dA + 512]);
    asm volatile("s_waitcnt vmcnt(0)" ::: "memory");
    asm volatile("s_barrier" ::: "memory");

    #pragma unroll
    for (int t = 0; t < KSTEPS; ++t) {
        const int db = (t & 1) * BUF2_U;
        const int eb = db ^ BUF2_U;
        // DMA for step t+1 -> other buffer (its last reads were step t-1,
        // consumed before the previous barrier)
        if (t + 1 < KSTEPS) {
            const int ko = (t + 1) * 32;
            gll16(sA_hi + ko,         &smem[eb + dA]);
            gll16(sA_hi + 16*D_ + ko, &smem[eb + dA + 512]);
            gll16(sA_lo + ko,         &smem[eb + 4096 + dA]);
            gll16(sA_lo + 16*D_ + ko, &smem[eb + 4096 + dA + 512]);
            gll16(sB_hi + ko,         &smem[eb + 8192 + dA]);
            gll16(sB_hi + 16*D_ + ko, &smem[eb + 8192 + dA + 512]);
            gll16(sB_lo + ko,         &smem[eb + 12288 + dA]);
            gll16(sB_lo + 16*D_ + ko, &smem[eb + 12288 + dA + 512]);
        }
        // fragment reads for this step
        bf16x8 ah[4], al[4], bh[4], bl[4];
        #pragma unroll
        for (int r = 0; r < 4; ++r) {
            ah[r] = *(const bf16x8*)&smem[db + offA[r]];
            al[r] = *(const bf16x8*)&smem[db + offA[r] + 4096];
        }
        #pragma unroll
        for (int c = 0; c < 4; ++c) {
            bh[c] = *(const bf16x8*)&smem[db + offB[c]];
            bl[c] = *(const bf16x8*)&smem[db + offB[c] + 4096];
        }
        // MFMA bursts (term order fixed: hh, hl, lh)
        __builtin_amdgcn_s_setprio(1);
        #pragma unroll
        for (int r = 0; r < 4; ++r)
            #pragma unroll
            for (int c = 0; c < 4; ++c)
                acc[r][c] = __builtin_amdgcn_mfma_f32_16x16x32_bf16(ah[r], bh[c], acc[r][c], 0, 0, 0);
        #pragma unroll
        for (int r = 0; r < 4; ++r)
            #pragma unroll
            for (int c = 0; c < 4; ++c)
                acc[r][c] = __builtin_amdgcn_mfma_f32_16x16x32_bf16(ah[r], bl[c], acc[r][c], 0, 0, 0);
        #pragma unroll
        for (int r = 0; r < 4; ++r)
            #pragma unroll
            for (int c = 0; c < 4; ++c)
                acc[r][c] = __builtin_amdgcn_mfma_f32_16x16x32_bf16(al[r], bh[c], acc[r][c], 0, 0, 0);
        __builtin_amdgcn_s_setprio(0);
        // drain this step's DMAs (flight time = frag reads + MFMA burst;
        // the residual stall is covered by the co-resident block)
        if (t + 1 < KSTEPS) {
            asm volatile("s_waitcnt vmcnt(0)" ::: "memory");
            asm volatile("s_barrier" ::: "memory");
        }
    }

    // ---- epilogue: bias + GELU + W2 dot, f64 reduce over h, atomic into scores
    float b1v[4], w2v[4];
    #pragma unroll
    for (int c = 0; c < 4; ++c) {
        int hg = h0 + wcn*64 + c*16 + lm;
        bool ok = (hg < H_);
        b1v[c] = ok ? b1[hg] : 0.0f;
        w2v[c] = ok ? W2[hg] : 0.0f;
    }
    const float is2 = 0.70710678118654752440f;
    #pragma unroll
    for (int r = 0; r < 4; ++r) {
        #pragma unroll
        for (int i = 0; i < 4; ++i) {
            float ps = 0.0f;
            #pragma unroll
            for (int c = 0; c < 4; ++c) {
                float z  = acc[r][c][i] + b1v[c];
                float gl = 0.5f * z * (1.0f + erff(z * is2));
                ps = fmaf(gl, w2v[c], ps);
            }
            double psd = (double)ps;
            psd += __shfl_xor(psd, 1);
            psd += __shfl_xor(psd, 2);
            psd += __shfl_xor(psd, 4);
            psd += __shfl_xor(psd, 8);
            if (lm == 0)
                atomicAdd(&scores[t0 + wr*64 + r*16 + lq*4 + i], psd);
        }
    }
}

// ============================================================
// Kernel A (fallback, smaller-ws version): in-loop LN+split staging
// ============================================================
__launch_bounds__(256)
__global__ void k_scores_fb(const float* __restrict__ emb, const float* __restrict__ ln_g,
                            const float* __restrict__ ln_b, const float2* __restrict__ stats,
                            const unsigned short* __restrict__ w1thi,
                            const unsigned short* __restrict__ w1tlo,
                            const float* __restrict__ b1, const float* __restrict__ W2,
                            double* __restrict__ scores)
{
    __shared__ __align__(16) unsigned short sAhi[128*40];
    __shared__ __align__(16) unsigned short sAlo[128*40];
    __shared__ __align__(16) unsigned short sBhi[128*40];
    __shared__ __align__(16) unsigned short sBlo[128*40];
    __shared__ float sS1[128], sS2[128];

    const int tid = threadIdx.x;
    const int blk = blockIdx.x;
    const int xcd = blk & 7, slot = blk >> 3;
    const int lin = xcd * 176 + slot;
    const int tt = lin / 11, hh = lin - tt * 11;
    const int t0 = tt * 128;
    const int h0 = hh * 128;

    if (tid < 128) {
        float2 st = stats[t0 + tid];
        sS1[tid] = st.x; sS2[tid] = st.y;
    }
    f32x4 acc[4][4];
    #pragma unroll
    for (int r = 0; r < 4; ++r)
        #pragma unroll
        for (int c = 0; c < 4; ++c) acc[r][c] = (f32x4){0.f, 0.f, 0.f, 0.f};
    const int l = tid & 63, w = tid >> 6;
    const int lm = l & 15, lq = l >> 4;
    const int wr = (w >> 1) * 64;
    const int wc = (w & 1) * 64;
    __syncthreads();

    for (int kc = 0; kc < D_; kc += 32) {
        #pragma unroll
        for (int r2 = 0; r2 < 2; ++r2) {
            int g = tid + r2 * 256;
            int row = g >> 2, oct = g & 3;
            size_t src = (size_t)(h0 + row) * D_ + kc + oct * 8;
            int dst = row * 40 + oct * 8;
            *(bf16x8*)&sBhi[dst] = *(const bf16x8*)&w1thi[src];
            *(bf16x8*)&sBlo[dst] = *(const bf16x8*)&w1tlo[src];
        }
        #pragma unroll
        for (int r2 = 0; r2 < 2; ++r2) {
            int g = tid + r2 * 256;
            int tk = g >> 2, oct = g & 3;
            int tg = t0 + tk, dg = kc + oct * 8;
            const float* ep = emb + (size_t)tg * D_ + dg;
            float s1 = sS1[tk], ns2 = -sS2[tk];
            union { unsigned short s[8]; bf16x8 v; } hi, lo;
            #pragma unroll
            for (int j = 0; j < 8; ++j) {
                float t  = fmaf(ep[j], s1, ns2);
                float xn = fmaf(t, ln_g[dg + j], ln_b[dg + j]);
                unsigned short hb = f2bf(xn);
                float hf = __uint_as_float((uint32_t)hb << 16);
                hi.s[j] = hb;
                lo.s[j] = f2bf(xn - hf);
            }
            int dst = tk * 40 + oct * 8;
            *(bf16x8*)&sAhi[dst] = hi.v;
            *(bf16x8*)&sAlo[dst] = lo.v;
        }
        __syncthreads();
        bf16x8 ah[4], al[4], bh[4], bl[4];
        #pragma unroll
        for (int r = 0; r < 4; ++r) {
            int off = (wr + r * 16 + lm) * 40 + lq * 8;
            ah[r] = *(const bf16x8*)&sAhi[off];
            al[r] = *(const bf16x8*)&sAlo[off];
        }
        #pragma unroll
        for (int c = 0; c < 4; ++c) {
            int off = (wc + c * 16 + lm) * 40 + lq * 8;
            bh[c] = *(const bf16x8*)&sBhi[off];
            bl[c] = *(const bf16x8*)&sBlo[off];
        }
        #pragma unroll
        for (int r = 0; r < 4; ++r)
            #pragma unroll
            for (int c = 0; c < 4; ++c) {
                acc[r][c] = __builtin_amdgcn_mfma_f32_16x16x32_bf16(ah[r], bh[c], acc[r][c], 0, 0, 0);
                acc[r][c] = __builtin_amdgcn_mfma_f32_16x16x32_bf16(ah[r], bl[c], acc[r][c], 0, 0, 0);
                acc[r][c] = __builtin_amdgcn_mfma_f32_16x16x32_bf16(al[r], bh[c], acc[r][c], 0, 0, 0);
            }
        __syncthreads();
    }
    float b1v[4], w2v[4];
    #pragma unroll
    for (int c = 0; c < 4; ++c) {
        int hg = h0 + wc + c * 16 + lm;
        bool ok = (hg < H_);
        b1v[c] = ok ? b1[hg] : 0.0f;
        w2v[c] = ok ? W2[hg] : 0.0f;
    }
    const float is2 = 0.70710678118654752440f;
    #pragma unroll
    for (int r = 0; r < 4; ++r) {
        #pragma unroll
        for (int i = 0; i < 4; ++i) {
            float ps = 0.0f;
            #pragma unroll
            for (int c = 0; c < 4; ++c) {
                float z  = acc[r][c][i] + b1v[c];
                float gl = 0.5f * z * (1.0f + erff(z * is2));
                ps = fmaf(gl, w2v[c], ps);
            }
            double psd = (double)ps;
            psd += __shfl_xor(psd, 1);
            psd += __shfl_xor(psd, 2);
            psd += __shfl_xor(psd, 4);
            psd += __shfl_xor(psd, 8);
            if (lm == 0)
                atomicAdd(&scores[t0 + wr + r * 16 + lq * 4 + i], psd);
        }
    }
}

// ============================================================
// JAX threefry2x32
// ============================================================
__device__ inline void tf2x32(uint32_t k0, uint32_t k1, uint32_t x0, uint32_t x1,
                              uint32_t& o0, uint32_t& o1)
{
    const uint32_t ks2 = k0 ^ k1 ^ 0x1BD11BDAu;
    x0 += k0; x1 += k1;
#define ROT_(v,d) (((v) << (d)) | ((v) >> (32 - (d))))
#define RND_(R) { x0 += x1; x1 = ROT_(x1, R); x1 ^= x0; }
    RND_(13) RND_(15) RND_(26) RND_(6)
    x0 += k1;  x1 += ks2 + 1u;
    RND_(17) RND_(29) RND_(16) RND_(24)
    x0 += ks2; x1 += k0 + 2u;
    RND_(13) RND_(15) RND_(26) RND_(6)
    x0 += k0;  x1 += k1 + 3u;
    RND_(17) RND_(29) RND_(16) RND_(24)
    x0 += k1;  x1 += ks2 + 4u;
    RND_(13) RND_(15) RND_(26) RND_(6)
    x0 += ks2; x1 += k0 + 5u;
    o0 = x0; o1 = x1;
#undef RND_
#undef ROT_
}

// ============================================================
// Kernel B: gumbel pert + MSB radix-select k-th largest + indicator counts
// ============================================================
__launch_bounds__(256)
__global__ void k_topk(const double* __restrict__ scores, const float* __restrict__ attn,
                       const float* __restrict__ b2, int* __restrict__ cnt)
{
    __shared__ unsigned long long keys[2048];
    __shared__ unsigned int hist[256];
    __shared__ unsigned int wsum[4];
    __shared__ unsigned int selDigit, selBase;
    __shared__ double red[4];

    const int tid = threadIdx.x;
    const int blk = blockIdx.x;
    const int j = blk / 40;
    const int s = (blk % 40) >> 3;
    const int b = blk & 7;

    uint32_t kk0, kk1;
    tf2x32(0u, 42u, 0u, (uint32_t)j, kk0, kk1);

    double tsum = 0.0;
    for (int t = tid; t < T_; t += 256) tsum += (double)attn[b * T_ + t];
    for (int m = 32; m; m >>= 1) tsum += __shfl_xor(tsum, m);
    if ((tid & 63) == 0) red[tid >> 6] = tsum;
    __syncthreads();
    const double Teff = red[0] + red[1] + red[2] + red[3];
    const float rhos[5] = {0.1f, 0.2f, 0.3f, 0.4f, 0.5f};
    int kst = (int)(rhos[j] * (float)Teff);
    if (kst < 1) kst = 1;

    const double bb2 = (double)b2[0];
    #pragma unroll
    for (int r = 0; r < 8; ++r) {
        int t = tid + r * 256;
        int f = (s * 8 + b) * T_ + t;
        uint32_t o0, o1;
        tf2x32(kk0, kk1, 0u, (uint32_t)f, o0, o1);
        uint32_t bits = o0 ^ o1;
        float u = __uint_as_float((bits >> 9) | 0x3f800000u) - 1.0f;
        float a1 = (float)((double)u + (double)1e-6f);
        float la = (float)log((double)a1);
        float m1 = (float)((double)1e-6f - (double)la);
        float lb = (float)log((double)m1);
        float noise = -lb;
        float av = attn[b * T_ + t];
        double pv = (av == 0.0f) ? -1e9 : (scores[b * T_ + t] + bb2 + (double)noise);
        unsigned long long uu = (unsigned long long)__double_as_longlong(pv);
        keys[t] = (uu >> 63) ? ~uu : (uu | 0x8000000000000000ull);
    }
    __syncthreads();

    unsigned long long pfx = 0;
    unsigned int plo = (unsigned int)(2048 - kst);
    const int lane = tid & 63, wv = tid >> 6;
    for (int pass = 0; pass < 8; ++pass) {
        const int shift = 56 - 8 * pass;
        const unsigned long long maskhi = (pass == 0) ? 0ull : (~0ull << (64 - 8 * pass));
        hist[tid] = 0;
        __syncthreads();
        #pragma unroll
        for (int r = 0; r < 8; ++r) {
            unsigned long long kk = keys[tid + r * 256];
            if ((kk & maskhi) == pfx)
                atomicAdd(&hist[(unsigned int)((kk >> shift) & 255ull)], 1u);
        }
        __syncthreads();
        unsigned int own = hist[tid];
        int val = (int)own;
        #pragma unroll
        for (int off = 1; off < 64; off <<= 1) {
            int n = __shfl_up(val, off);
            if (lane >= off) val += n;
        }
        if (lane == 63) wsum[wv] = (unsigned int)val;
        __syncthreads();
        unsigned int woff = 0;
        for (int q = 0; q < wv; ++q) woff += wsum[q];
        unsigned int incl = (unsigned int)val + woff;
        unsigned int excl = incl - own;
        if (own > 0 && plo >= excl && plo < incl) { selDigit = (unsigned int)tid; selBase = excl; }
        __syncthreads();
        pfx |= ((unsigned long long)selDigit << shift);
        plo -= selBase;
        __syncthreads();
    }

    #pragma unroll
    for (int r = 0; r < 8; ++r) {
        int t = tid + r * 256;
        if (keys[t] >= pfx) atomicAdd(&cnt[(j * 8 + b) * T_ + t], 1);
    }
}

// ============================================================
// Kernel C: finalize g = cnt/5, write g & g_sweep & rho_eff, row sums
// ============================================================
__launch_bounds__(256)
__global__ void k_gfin(const int* __restrict__ cnt, const float* __restrict__ attn,
                       float* __restrict__ out, double* __restrict__ sumeff,
                       double* __restrict__ sumatt, double* __restrict__ sumg)
{
    __shared__ double redA[4], redB[4], redC[4];
    const int j = blockIdx.x >> 3, b = blockIdx.x & 7;
    const int tid = threadIdx.x;
    double sg = 0.0, se = 0.0, sa = 0.0;
    for (int t = tid; t < T_; t += 256) {
        int c = cnt[(j * 8 + b) * T_ + t];
        float g  = (float)c / 5.0f;
        float av = attn[b * T_ + t];
        out[OUT_GSW + (j * 8 + b) * T_ + t] = g;
        if (j == 4) out[OUT_G + b * T_ + t] = g;
        sg += (double)g;
        se += (double)(av * g);
        sa += (double)av;
    }
    for (int m = 32; m; m >>= 1) { sg += __shfl_xor(sg, m); se += __shfl_xor(se, m); sa += __shfl_xor(sa, m); }
    if ((tid & 63) == 0) { redA[tid>>6] = sg; redB[tid>>6] = se; redC[tid>>6] = sa; }
    __syncthreads();
    if (tid == 0) {
        sg = redA[0]+redA[1]+redA[2]+redA[3];
        se = redB[0]+redB[1]+redB[2]+redB[3];
        sa = redC[0]+redC[1]+redC[2]+redC[3];
        sumg[j*8+b] = sg; sumeff[j*8+b] = se;
        if (j == 0) sumatt[b] = sa;
        out[OUT_RHOEFF + j*8 + b] = (float)sg / (float)sa;
    }
}

// ============================================================
// Kernel D: pooled weighted sums over tok = emb_table[ids] (512 blocks)
// ============================================================
__launch_bounds__(256)
__global__ void k_pool(const int* __restrict__ ids, const float* __restrict__ attn,
                       const float* __restrict__ out, const float* __restrict__ emb_table,
                       double* __restrict__ predw, double* __restrict__ fullw)
{
    __shared__ int   sid[128];
    __shared__ float sw[6][128];
    const int blk = blockIdx.x;
    const int b  = blk >> 6;            // 8
    const int dc = (blk >> 4) & 3;      // 4
    const int tc = blk & 15;            // 16
    const int tid = threadIdx.x;
    const int d = dc * 256 + tid;
    if (tid < 128) {
        int t = tc * 128 + tid;
        sid[tid] = ids[b * T_ + t];
        float av = attn[b * T_ + t];
        sw[0][tid] = av;
        #pragma unroll
        for (int j = 0; j < 5; ++j) {
            float g = out[OUT_GSW + (j * 8 + b) * T_ + t];
            sw[1 + j][tid] = av * g;
        }
    }
    __syncthreads();
    double acc[6] = {0,0,0,0,0,0};
    #pragma unroll 4
    for (int i = 0; i < 128; ++i) {
        float val = emb_table[(size_t)sid[i] * D_ + d];
        #pragma unroll
        for (int c = 0; c < 6; ++c) acc[c] += (double)(val * sw[c][i]);
    }
    atomicAdd(&fullw[b * D_ + d], acc[0]);
    #pragma unroll
    for (int j = 0; j < 5; ++j)
        atomicAdd(&predw[(j * 8 + b) * D_ + d], acc[1 + j]);
}

// ============================================================
// Kernel E: losses (5 blocks, one per rho) + finalize
// ============================================================
__launch_bounds__(256)
__global__ void k_loss(const double* __restrict__ predw, const double* __restrict__ fullw,
                       const double* __restrict__ sumeff, const double* __restrict__ sumatt,
                       float* __restrict__ out, double* __restrict__ lrws)
{
    __shared__ double red[4];
    const int j = blockIdx.x;
    const int tid = threadIdx.x;
    double p = 0.0;
    for (int i = tid; i < B_ * D_; i += 256) {
        int b = i >> 10;
        double dF = sumatt[b];        if (dF < 1e-6) dF = 1e-6;
        double dE = sumeff[j*8 + b];  if (dE < 1e-6) dE = 1e-6;
        double diff = predw[j * B_ * D_ + i] / dE - fullw[i] / dF;
        p += diff * diff;
    }
    for (int m = 32; m; m >>= 1) p += __shfl_xor(p, m);
    if ((tid & 63) == 0) red[tid >> 6] = p;
    __syncthreads();
    if (tid == 0) {
        double t = red[0] + red[1] + red[2] + red[3];
        float lr = (float)(t / (double)(B_ * D_));
        out[OUT_LOSS + j] = lr;
        lrws[j] = (double)lr;
    }
}

__launch_bounds__(64)
__global__ void k_lfin(const double* __restrict__ lrws, float* __restrict__ out)
{
    if (threadIdx.x == 0) {
        float srec = 0.0f;
        for (int j = 0; j < 5; ++j) srec += (float)lrws[j];
        out[OUT_RECON] = srec / 5.0f;
    }
}

extern "C" void kernel_launch(void* const* d_in, const int* in_sizes, int n_in,
                              void* d_out, int out_size, void* d_ws, size_t ws_size,
                              hipStream_t stream)
{
    const int*   ids  = (const int*)  d_in[0];
    const float* emb  = (const float*)d_in[1];
    const float* attn = (const float*)d_in[2];
    const float* ln_g = (const float*)d_in[3];
    const float* ln_b = (const float*)d_in[4];
    const float* W1   = (const float*)d_in[5];
    const float* b1   = (const float*)d_in[6];
    const float* W2   = (const float*)d_in[7];
    const float* b2   = (const float*)d_in[8];
    const float* et   = (const float*)d_in[9];
    float* out = (float*)d_out;
    char*  ws  = (char*)d_ws;

    double* scores = (double*)(ws + WS_SCORES);
    int*    cnt    = (int*)   (ws + WS_CNT);
    double* predw  = (double*)(ws + WS_PREDW);
    double* fullw  = (double*)(ws + WS_FULLW);
    double* sumeff = (double*)(ws + WS_SUMEFF);
    double* sumatt = (double*)(ws + WS_SUMATT);
    double* sumg   = (double*)(ws + WS_SUMG);
    double* lrws   = (double*)(ws + WS_LR);
    float2* stats  = (float2*)(ws + WS_STATS);
    unsigned short* w1thi = (unsigned short*)(ws + WS_W1THI);
    unsigned short* w1tlo = (unsigned short*)(ws + WS_W1TLO);
    unsigned short* ahi   = (unsigned short*)(ws + WS_AHI);
    unsigned short* alo   = (unsigned short*)(ws + WS_ALO);

    hipMemsetAsync(d_ws, 0, WS_ZERO_BYTES, stream);

    k_w1t<<<48*32, 256, 0, stream>>>(W1, w1thi, w1tlo);
    if (ws_size >= WS_FULL_END) {
        k_asplit<<<NTOK/64, 256, 0, stream>>>(emb, attn, ln_g, ln_b, ahi, alo);
        k_scores8<<<1536, 256, 0, stream>>>(ahi, alo, w1thi, w1tlo, b1, W2, scores);
    } else {
        k_stats<<<NTOK/64, 256, 0, stream>>>(emb, attn, stats);
        k_scores_fb<<<1408, 256, 0, stream>>>(emb, ln_g, ln_b, stats, w1thi, w1tlo,
                                              b1, W2, scores);
    }
    k_topk<<<NRHO * NSAMP * B_, 256, 0, stream>>>(scores, attn, b2, cnt);
    k_gfin<<<NRHO * B_, 256, 0, stream>>>(cnt, attn, out, sumeff, sumatt, sumg);
    k_pool<<<512, 256, 0, stream>>>(ids, attn, out, et, predw, fullw);
    k_loss<<<NRHO, 256, 0, stream>>>(predw, fullw, sumeff, sumatt, out, lrws);
    k_lfin<<<1, 64, 0, stream>>>(lrws, out);
}

// Round 9
// 475.674 us; speedup vs baseline: 1.0309x; 1.0309x over previous
//
#include <hip/hip_runtime.h>
#include <math.h>
#include <stdint.h>

#define B_ 8
#define T_ 2048
#define D_ 1024
#define H_ 1365
#define HPAD 1536
#define NTOK (B_*T_)
#define NSAMP 5
#define NRHO 5

typedef float  f32x4  __attribute__((ext_vector_type(4)));
typedef __bf16 bf16x8 __attribute__((ext_vector_type(8)));

// ---- ws layout (bytes) ----
#define WS_SCORES 0                              // f64 [16384]
#define WS_CNT    (WS_SCORES + NTOK*8)           // int [5*8*2048]
#define WS_PREDW  (WS_CNT + NRHO*B_*T_*4)        // f64 [5][8][1024]
#define WS_FULLW  (WS_PREDW + NRHO*B_*D_*8)      // f64 [8][1024]
#define WS_SUMEFF (WS_FULLW + B_*D_*8)           // f64 [5][8]
#define WS_SUMATT (WS_SUMEFF + NRHO*B_*8)        // f64 [8]
#define WS_SUMG   (WS_SUMATT + B_*8)             // f64 [5][8]
#define WS_LR     (WS_SUMG + NRHO*B_*8)          // f64 [5]
#define WS_ZERO_BYTES (WS_LR + NRHO*8)
#define WS_STATS  WS_ZERO_BYTES                  // float2 [16384] (fallback path)
#define WS_W1THI  (WS_STATS + NTOK*8)            // ushort [1536][1024]
#define WS_W1TLO  (WS_W1THI + (size_t)HPAD*D_*2) // ushort [1536][1024]
#define WS_AHI    (WS_W1TLO + (size_t)HPAD*D_*2) // ushort [16384][1024]
#define WS_ALO    (WS_AHI + (size_t)NTOK*D_*2)   // ushort [16384][1024]
#define WS_FULL_END (WS_ALO + (size_t)NTOK*D_*2)

// ---- out layout (f32 elements) ----
#define OUT_G      0
#define OUT_GSW    16384
#define OUT_RECON  98304
#define OUT_LOSS   98305
#define OUT_RHOEFF 98310

__device__ inline unsigned short f2bf(float x) {   // RNE f32 -> bf16 bits
    uint32_t u = __float_as_uint(x);
    return (unsigned short)((u + 0x7FFFu + ((u >> 16) & 1u)) >> 16);
}

// ============================================================
// Prep: W1 [1024][1365] -> W1T hi/lo bf16 [1536][1024] (k-contiguous, zero-padded)
// ============================================================
__launch_bounds__(256)
__global__ void k_w1t(const float* __restrict__ W1, unsigned short* __restrict__ hi,
                      unsigned short* __restrict__ lo)
{
    __shared__ float tile[32][33];
    const int tid = threadIdx.x;
    const int bk = blockIdx.x & 31;
    const int bh = blockIdx.x >> 5;
    const int k0 = bk * 32, h0 = bh * 32;
    const int a = tid & 31, b = tid >> 5;
    #pragma unroll
    for (int i = 0; i < 4; ++i) {
        int k = k0 + b + i * 8;
        int h = h0 + a;
        tile[b + i*8][a] = (h < H_) ? W1[(size_t)k * H_ + h] : 0.0f;
    }
    __syncthreads();
    #pragma unroll
    for (int i = 0; i < 4; ++i) {
        int hrow = h0 + b + i * 8;
        int kcol = k0 + a;
        float v = tile[a][b + i*8];
        unsigned short hb = f2bf(v);
        float hf = __uint_as_float((uint32_t)hb << 16);
        unsigned short lb = f2bf(v - hf);
        size_t dst = (size_t)hrow * D_ + kcol;
        hi[dst] = hb; lo[dst] = lb;
    }
}

// ============================================================
// Prep: fused LN stats (f64) + f32 transform + bf16 hi/lo split -> Ahi/Alo
// ============================================================
__launch_bounds__(256)
__global__ void k_asplit(const float* __restrict__ emb, const float* __restrict__ attn,
                         const float* __restrict__ ln_g, const float* __restrict__ ln_b,
                         unsigned short* __restrict__ ahi, unsigned short* __restrict__ alo)
{
    const int tid = threadIdx.x, l = tid & 63, w = tid >> 6;
    const int t0 = blockIdx.x * 64;
    for (int tk = w; tk < 64; tk += 4) {
        const int tg = t0 + tk;
        const float av = attn[tg];
        const float* row = emb + (size_t)tg * D_;
        float rv[16];
        double s1 = 0.0, s2 = 0.0;
        #pragma unroll
        for (int i = 0; i < 16; ++i) {
            rv[i] = row[i*64 + l];
            double x = (double)rv[i] * (double)av;
            s1 += x; s2 += x * x;
        }
        for (int m = 32; m; m >>= 1) { s1 += __shfl_xor(s1, m); s2 += __shfl_xor(s2, m); }
        double mean = s1 / (double)D_;
        double var  = s2 / (double)D_ - mean * mean;
        double inv  = 1.0 / sqrt(var + 1e-5);
        float sc  = (float)((double)av * inv);
        float nsh = -(float)(mean * inv);
        #pragma unroll
        for (int i = 0; i < 16; ++i) {
            int k = i * 64 + l;
            float t  = fmaf(rv[i], sc, nsh);
            float xn = fmaf(t, ln_g[k], ln_b[k]);
            unsigned short hb = f2bf(xn);
            float hf = __uint_as_float((uint32_t)hb << 16);
            size_t dst = (size_t)tg * D_ + k;
            ahi[dst] = hb;
            alo[dst] = f2bf(xn - hf);
        }
    }
}

// (fallback path prep: per-token stats only)
__launch_bounds__(256)
__global__ void k_stats(const float* __restrict__ emb, const float* __restrict__ attn,
                        float2* __restrict__ stats)
{
    const int tid = threadIdx.x, l = tid & 63, w = tid >> 6;
    const int t0 = blockIdx.x * 64;
    for (int tk = w; tk < 64; tk += 4) {
        const int tg = t0 + tk;
        const float av = attn[tg];
        const float* row = emb + (size_t)tg * D_;
        double s1 = 0.0, s2 = 0.0;
        #pragma unroll
        for (int i = 0; i < D_/64; ++i) {
            double x = (double)row[i*64 + l] * (double)av;
            s1 += x; s2 += x * x;
        }
        for (int m = 32; m; m >>= 1) { s1 += __shfl_xor(s1, m); s2 += __shfl_xor(s2, m); }
        if (l == 0) {
            double mean = s1 / (double)D_;
            double var  = s2 / (double)D_ - mean * mean;
            double inv  = 1.0 / sqrt(var + 1e-5);
            stats[tg] = make_float2((float)((double)av * inv), (float)(mean * inv));
        }
    }
}

// ============================================================
// Kernel A: 3-term split GEMM with cross-step register prefetch (R3 exact —
// session-best measured 154us, MfmaUtil 44.6%, FETCH 115MB).
//
// BM=128, BN=256, BK=32, 512 thr (8 waves 2Mx4N, 64x64/wave, 4x4 16x16x32 frags).
// Grid 768 = 128 M x 6 N tiles; mm-major-within-XCD swizzle (FETCH-minimal).
// Asymmetric LDS rings, 144 KiB: hi-ring 4x24KB (DMA distance 3),
// lo-ring 2x24KB (distance 1). hi-frags(t) prefetched into regs during t-1;
// lo-frags read in-step (covered by the hh burst). One counted vmcnt(3) +
// one barrier per step; hi(t+3)'s 3 DMAs stay in flight across the barrier.
//
// Post-session note: four structural alternatives all regressed —
//  B->regs distance-2 (R4 267us, R6 283us: L2-topology tradeoff, FETCH 2x),
//  full reg-prefetch (R7 192us: compiler sinks prefetch ds_reads to barrier),
//  2 blocks/CU BN=128 (R8 204us: FETCH +47%, 2x drains). This structure is
//  at the documented m97-class 2-barrier-loop ceiling; step ~= LDS + MFMA.
// ============================================================
#define HIBUF_U 12288        // ushorts per hi buffer (Ahi 4096 | Bhi 8192)
#define LOBUF_U 12288        // ushorts per lo buffer (Alo 4096 | Blo 8192)
#define LORING0 49152        // 4*HIBUF_U
#define KSTEPS 32

__device__ __forceinline__ void gll16(const unsigned short* g, unsigned short* l)
{
    __builtin_amdgcn_global_load_lds((const __attribute__((address_space(1))) void*)g,
                                     (__attribute__((address_space(3))) void*)l, 16, 0, 0);
}

__launch_bounds__(512, 2)
__global__ void k_scores8(const unsigned short* __restrict__ ahi,
                          const unsigned short* __restrict__ alo,
                          const unsigned short* __restrict__ w1thi,
                          const unsigned short* __restrict__ w1tlo,
                          const float* __restrict__ b1, const float* __restrict__ W2,
                          double* __restrict__ scores)
{
    __shared__ __align__(16) unsigned short smem[LORING0 + 2*LOBUF_U];   // 144 KiB

    const int tid = threadIdx.x;
    const int blk = blockIdx.x;
    // XCD-aware swizzle: 768 blocks, 8 XCDs, 96/XCD; hh fastest within chunk
    const int lin = (blk & 7) * 96 + (blk >> 3);
    const int mm = lin / 6, hh = lin - mm * 6;
    const int t0 = mm * 128;
    const int h0 = hh * 256;

    const int l  = tid & 63, w = tid >> 6;
    const int wr = w >> 2, wcn = w & 3;            // wave row/col group
    const int lm = l & 15, lq = l >> 4;

    // ---- staging: per-lane global src (inverse-swizzled), wave-uniform LDS dst
    const int lrow  = l >> 2;                      // 0..15 within 16-row chunk
    const int lslot = (l & 3) ^ ((l >> 3) & 3);    // logical 16B slot for phys slot l&3
    const unsigned short* sA_hi  = ahi   + (size_t)(t0 + w*16 + lrow) * D_ + lslot*8;
    const unsigned short* sA_lo  = alo   + (size_t)(t0 + w*16 + lrow) * D_ + lslot*8;
    const unsigned short* sB_hi0 = w1thi + (size_t)(h0 + w*32 + lrow) * D_ + lslot*8;
    const unsigned short* sB_hi1 = sB_hi0 + 16*D_;
    const unsigned short* sB_lo0 = w1tlo + (size_t)(h0 + w*32 + lrow) * D_ + lslot*8;
    const unsigned short* sB_lo1 = sB_lo0 + 16*D_;
    const int dA  = w*512;                          // buffer-relative A dst
    const int dB0 = 4096 + w*1024, dB1 = dB0 + 512; // buffer-relative B dst

    // ---- fragment read offsets (swizzled): phys_slot = lq ^ ((row>>1)&3)
    const int sw8 = (lq ^ ((lm >> 1) & 3)) * 8;
    int offA[4], offB[4];
    #pragma unroll
    for (int r = 0; r < 4; ++r) offA[r] = (wr*64 + r*16 + lm)*32 + sw8;
    #pragma unroll
    for (int c = 0; c < 4; ++c) offB[c] = 4096 + (wcn*64 + c*16 + lm)*32 + sw8;

    f32x4 acc[4][4];
    #pragma unroll
    for (int r = 0; r < 4; ++r)
        #pragma unroll
        for (int c = 0; c < 4; ++c) acc[r][c] = (f32x4){0.f, 0.f, 0.f, 0.f};

    // ---- prologue: hi(0), lo(0), hi(1), hi(2); drain all but hi(2)
    gll16(sA_hi,       &smem[0*HIBUF_U + dA]);
    gll16(sB_hi0,      &smem[0*HIBUF_U + dB0]);
    gll16(sB_hi1,      &smem[0*HIBUF_U + dB1]);
    gll16(sA_lo,       &smem[LORING0 + dA]);
    gll16(sB_lo0,      &smem[LORING0 + dB0]);
    gll16(sB_lo1,      &smem[LORING0 + dB1]);
    gll16(sA_hi  + 32, &smem[1*HIBUF_U + dA]);
    gll16(sB_hi0 + 32, &smem[1*HIBUF_U + dB0]);
    gll16(sB_hi1 + 32, &smem[1*HIBUF_U + dB1]);
    gll16(sA_hi  + 64, &smem[2*HIBUF_U + dA]);
    gll16(sB_hi0 + 64, &smem[2*HIBUF_U + dB0]);
    gll16(sB_hi1 + 64, &smem[2*HIBUF_U + dB1]);
    asm volatile("s_waitcnt vmcnt(3)" ::: "memory");
    asm volatile("s_barrier" ::: "memory");

    // ---- prefetch hi-frags(0) into register set 0
    bf16x8 ahp[2][4], bhp[2][4];
    #pragma unroll
    for (int r = 0; r < 4; ++r) ahp[0][r] = *(const bf16x8*)&smem[offA[r]];
    #pragma unroll
    for (int c = 0; c < 4; ++c) bhp[0][c] = *(const bf16x8*)&smem[offB[c]];

    #pragma unroll
    for (int t = 0; t < KSTEPS; ++t) {
        const int cur = t & 1, nxt = (t + 1) & 1;
        const int lobase = LORING0 + (t & 1) * LOBUF_U;
        // issue DMA lo(t+1) (oldest-of-new first), then hi(t+3)
        if (t + 1 < KSTEPS) {
            const int lb = LORING0 + ((t + 1) & 1) * LOBUF_U;
            const int ko = (t + 1) * 32;
            gll16(sA_lo  + ko, &smem[lb + dA]);
            gll16(sB_lo0 + ko, &smem[lb + dB0]);
            gll16(sB_lo1 + ko, &smem[lb + dB1]);
        }
        if (t + 3 < KSTEPS) {
            const int hb = ((t + 3) & 3) * HIBUF_U;
            const int ko = (t + 3) * 32;
            gll16(sA_hi  + ko, &smem[hb + dA]);
            gll16(sB_hi0 + ko, &smem[hb + dB0]);
            gll16(sB_hi1 + ko, &smem[hb + dB1]);
        }
        // lo-frag reads (this step) + hi-frag prefetch (next step)
        bf16x8 bl[4], al[4];
        #pragma unroll
        for (int c = 0; c < 4; ++c) bl[c] = *(const bf16x8*)&smem[lobase + offB[c]];
        #pragma unroll
        for (int r = 0; r < 4; ++r) al[r] = *(const bf16x8*)&smem[lobase + offA[r]];
        if (t + 1 < KSTEPS) {
            const int hb = ((t + 1) & 3) * HIBUF_U;
            #pragma unroll
            for (int r = 0; r < 4; ++r) ahp[nxt][r] = *(const bf16x8*)&smem[hb + offA[r]];
            #pragma unroll
            for (int c = 0; c < 4; ++c) bhp[nxt][c] = *(const bf16x8*)&smem[hb + offB[c]];
        }
        __builtin_amdgcn_s_setprio(1);
        #pragma unroll
        for (int r = 0; r < 4; ++r)
            #pragma unroll
            for (int c = 0; c < 4; ++c)
                acc[r][c] = __builtin_amdgcn_mfma_f32_16x16x32_bf16(ahp[cur][r], bhp[cur][c], acc[r][c], 0, 0, 0);
        #pragma unroll
        for (int r = 0; r < 4; ++r)
            #pragma unroll
            for (int c = 0; c < 4; ++c)
                acc[r][c] = __builtin_amdgcn_mfma_f32_16x16x32_bf16(ahp[cur][r], bl[c], acc[r][c], 0, 0, 0);
        #pragma unroll
        for (int r = 0; r < 4; ++r)
            #pragma unroll
            for (int c = 0; c < 4; ++c)
                acc[r][c] = __builtin_amdgcn_mfma_f32_16x16x32_bf16(al[r], bhp[cur][c], acc[r][c], 0, 0, 0);
        __builtin_amdgcn_s_setprio(0);
        // drain: leaves only hi(t+3) in flight (issued this step, 3 calls);
        // lo(t+1) and hi(t+2) were issued >=1 full step ago -> covered.
        if (t < KSTEPS - 3)      asm volatile("s_waitcnt vmcnt(3)" ::: "memory");
        else if (t < KSTEPS - 1) asm volatile("s_waitcnt vmcnt(0)" ::: "memory");
        if (t < KSTEPS - 1)      asm volatile("s_barrier" ::: "memory");
    }

    // ---- epilogue: bias + GELU + W2 dot, f64 reduce over h, atomic into scores
    float b1v[4], w2v[4];
    #pragma unroll
    for (int c = 0; c < 4; ++c) {
        int hg = h0 + wcn*64 + c*16 + lm;
        bool ok = (hg < H_);
        b1v[c] = ok ? b1[hg] : 0.0f;
        w2v[c] = ok ? W2[hg] : 0.0f;
    }
    const float is2 = 0.70710678118654752440f;
    #pragma unroll
    for (int r = 0; r < 4; ++r) {
        #pragma unroll
        for (int i = 0; i < 4; ++i) {
            float ps = 0.0f;
            #pragma unroll
            for (int c = 0; c < 4; ++c) {
                float z  = acc[r][c][i] + b1v[c];
                float gl = 0.5f * z * (1.0f + erff(z * is2));
                ps = fmaf(gl, w2v[c], ps);
            }
            double psd = (double)ps;
            psd += __shfl_xor(psd, 1);
            psd += __shfl_xor(psd, 2);
            psd += __shfl_xor(psd, 4);
            psd += __shfl_xor(psd, 8);
            if (lm == 0)
                atomicAdd(&scores[t0 + wr*64 + r*16 + lq*4 + i], psd);
        }
    }
}

// ============================================================
// Kernel A (fallback, smaller-ws version): in-loop LN+split staging
// ============================================================
__launch_bounds__(256)
__global__ void k_scores_fb(const float* __restrict__ emb, const float* __restrict__ ln_g,
                            const float* __restrict__ ln_b, const float2* __restrict__ stats,
                            const unsigned short* __restrict__ w1thi,
                            const unsigned short* __restrict__ w1tlo,
                            const float* __restrict__ b1, const float* __restrict__ W2,
                            double* __restrict__ scores)
{
    __shared__ __align__(16) unsigned short sAhi[128*40];
    __shared__ __align__(16) unsigned short sAlo[128*40];
    __shared__ __align__(16) unsigned short sBhi[128*40];
    __shared__ __align__(16) unsigned short sBlo[128*40];
    __shared__ float sS1[128], sS2[128];

    const int tid = threadIdx.x;
    const int blk = blockIdx.x;
    const int xcd = blk & 7, slot = blk >> 3;
    const int lin = xcd * 176 + slot;
    const int tt = lin / 11, hh = lin - tt * 11;
    const int t0 = tt * 128;
    const int h0 = hh * 128;

    if (tid < 128) {
        float2 st = stats[t0 + tid];
        sS1[tid] = st.x; sS2[tid] = st.y;
    }
    f32x4 acc[4][4];
    #pragma unroll
    for (int r = 0; r < 4; ++r)
        #pragma unroll
        for (int c = 0; c < 4; ++c) acc[r][c] = (f32x4){0.f, 0.f, 0.f, 0.f};
    const int l = tid & 63, w = tid >> 6;
    const int lm = l & 15, lq = l >> 4;
    const int wr = (w >> 1) * 64;
    const int wc = (w & 1) * 64;
    __syncthreads();

    for (int kc = 0; kc < D_; kc += 32) {
        #pragma unroll
        for (int r2 = 0; r2 < 2; ++r2) {
            int g = tid + r2 * 256;
            int row = g >> 2, oct = g & 3;
            size_t src = (size_t)(h0 + row) * D_ + kc + oct * 8;
            int dst = row * 40 + oct * 8;
            *(bf16x8*)&sBhi[dst] = *(const bf16x8*)&w1thi[src];
            *(bf16x8*)&sBlo[dst] = *(const bf16x8*)&w1tlo[src];
        }
        #pragma unroll
        for (int r2 = 0; r2 < 2; ++r2) {
            int g = tid + r2 * 256;
            int tk = g >> 2, oct = g & 3;
            int tg = t0 + tk, dg = kc + oct * 8;
            const float* ep = emb + (size_t)tg * D_ + dg;
            float s1 = sS1[tk], ns2 = -sS2[tk];
            union { unsigned short s[8]; bf16x8 v; } hi, lo;
            #pragma unroll
            for (int j = 0; j < 8; ++j) {
                float t  = fmaf(ep[j], s1, ns2);
                float xn = fmaf(t, ln_g[dg + j], ln_b[dg + j]);
                unsigned short hb = f2bf(xn);
                float hf = __uint_as_float((uint32_t)hb << 16);
                hi.s[j] = hb;
                lo.s[j] = f2bf(xn - hf);
            }
            int dst = tk * 40 + oct * 8;
            *(bf16x8*)&sAhi[dst] = hi.v;
            *(bf16x8*)&sAlo[dst] = lo.v;
        }
        __syncthreads();
        bf16x8 ah[4], al[4], bh[4], bl[4];
        #pragma unroll
        for (int r = 0; r < 4; ++r) {
            int off = (wr + r * 16 + lm) * 40 + lq * 8;
            ah[r] = *(const bf16x8*)&sAhi[off];
            al[r] = *(const bf16x8*)&sAlo[off];
        }
        #pragma unroll
        for (int c = 0; c < 4; ++c) {
            int off = (wc + c * 16 + lm) * 40 + lq * 8;
            bh[c] = *(const bf16x8*)&sBhi[off];
            bl[c] = *(const bf16x8*)&sBlo[off];
        }
        #pragma unroll
        for (int r = 0; r < 4; ++r)
            #pragma unroll
            for (int c = 0; c < 4; ++c) {
                acc[r][c] = __builtin_amdgcn_mfma_f32_16x16x32_bf16(ah[r], bh[c], acc[r][c], 0, 0, 0);
                acc[r][c] = __builtin_amdgcn_mfma_f32_16x16x32_bf16(ah[r], bl[c], acc[r][c], 0, 0, 0);
                acc[r][c] = __builtin_amdgcn_mfma_f32_16x16x32_bf16(al[r], bh[c], acc[r][c], 0, 0, 0);
            }
        __syncthreads();
    }
    float b1v[4], w2v[4];
    #pragma unroll
    for (int c = 0; c < 4; ++c) {
        int hg = h0 + wc + c * 16 + lm;
        bool ok = (hg < H_);
        b1v[c] = ok ? b1[hg] : 0.0f;
        w2v[c] = ok ? W2[hg] : 0.0f;
    }
    const float is2 = 0.70710678118654752440f;
    #pragma unroll
    for (int r = 0; r < 4; ++r) {
        #pragma unroll
        for (int i = 0; i < 4; ++i) {
            float ps = 0.0f;
            #pragma unroll
            for (int c = 0; c < 4; ++c) {
                float z  = acc[r][c][i] + b1v[c];
                float gl = 0.5f * z * (1.0f + erff(z * is2));
                ps = fmaf(gl, w2v[c], ps);
            }
            double psd = (double)ps;
            psd += __shfl_xor(psd, 1);
            psd += __shfl_xor(psd, 2);
            psd += __shfl_xor(psd, 4);
            psd += __shfl_xor(psd, 8);
            if (lm == 0)
                atomicAdd(&scores[t0 + wr + r * 16 + lq * 4 + i], psd);
        }
    }
}

// ============================================================
// JAX threefry2x32
// ============================================================
__device__ inline void tf2x32(uint32_t k0, uint32_t k1, uint32_t x0, uint32_t x1,
                              uint32_t& o0, uint32_t& o1)
{
    const uint32_t ks2 = k0 ^ k1 ^ 0x1BD11BDAu;
    x0 += k0; x1 += k1;
#define ROT_(v,d) (((v) << (d)) | ((v) >> (32 - (d))))
#define RND_(R) { x0 += x1; x1 = ROT_(x1, R); x1 ^= x0; }
    RND_(13) RND_(15) RND_(26) RND_(6)
    x0 += k1;  x1 += ks2 + 1u;
    RND_(17) RND_(29) RND_(16) RND_(24)
    x0 += ks2; x1 += k0 + 2u;
    RND_(13) RND_(15) RND_(26) RND_(6)
    x0 += k0;  x1 += k1 + 3u;
    RND_(17) RND_(29) RND_(16) RND_(24)
    x0 += k1;  x1 += ks2 + 4u;
    RND_(13) RND_(15) RND_(26) RND_(6)
    x0 += ks2; x1 += k0 + 5u;
    o0 = x0; o1 = x1;
#undef RND_
#undef ROT_
}

// ============================================================
// Kernel B: gumbel pert + MSB radix-select k-th largest + indicator counts
// ============================================================
__launch_bounds__(256)
__global__ void k_topk(const double* __restrict__ scores, const float* __restrict__ attn,
                       const float* __restrict__ b2, int* __restrict__ cnt)
{
    __shared__ unsigned long long keys[2048];
    __shared__ unsigned int hist[256];
    __shared__ unsigned int wsum[4];
    __shared__ unsigned int selDigit, selBase;
    __shared__ double red[4];

    const int tid = threadIdx.x;
    const int blk = blockIdx.x;
    const int j = blk / 40;
    const int s = (blk % 40) >> 3;
    const int b = blk & 7;

    uint32_t kk0, kk1;
    tf2x32(0u, 42u, 0u, (uint32_t)j, kk0, kk1);

    double tsum = 0.0;
    for (int t = tid; t < T_; t += 256) tsum += (double)attn[b * T_ + t];
    for (int m = 32; m; m >>= 1) tsum += __shfl_xor(tsum, m);
    if ((tid & 63) == 0) red[tid >> 6] = tsum;
    __syncthreads();
    const double Teff = red[0] + red[1] + red[2] + red[3];
    const float rhos[5] = {0.1f, 0.2f, 0.3f, 0.4f, 0.5f};
    int kst = (int)(rhos[j] * (float)Teff);
    if (kst < 1) kst = 1;

    const double bb2 = (double)b2[0];
    #pragma unroll
    for (int r = 0; r < 8; ++r) {
        int t = tid + r * 256;
        int f = (s * 8 + b) * T_ + t;
        uint32_t o0, o1;
        tf2x32(kk0, kk1, 0u, (uint32_t)f, o0, o1);
        uint32_t bits = o0 ^ o1;
        float u = __uint_as_float((bits >> 9) | 0x3f800000u) - 1.0f;
        float a1 = (float)((double)u + (double)1e-6f);
        float la = (float)log((double)a1);
        float m1 = (float)((double)1e-6f - (double)la);
        float lb = (float)log((double)m1);
        float noise = -lb;
        float av = attn[b * T_ + t];
        double pv = (av == 0.0f) ? -1e9 : (scores[b * T_ + t] + bb2 + (double)noise);
        unsigned long long uu = (unsigned long long)__double_as_longlong(pv);
        keys[t] = (uu >> 63) ? ~uu : (uu | 0x8000000000000000ull);
    }
    __syncthreads();

    unsigned long long pfx = 0;
    unsigned int plo = (unsigned int)(2048 - kst);
    const int lane = tid & 63, wv = tid >> 6;
    for (int pass = 0; pass < 8; ++pass) {
        const int shift = 56 - 8 * pass;
        const unsigned long long maskhi = (pass == 0) ? 0ull : (~0ull << (64 - 8 * pass));
        hist[tid] = 0;
        __syncthreads();
        #pragma unroll
        for (int r = 0; r < 8; ++r) {
            unsigned long long kk = keys[tid + r * 256];
            if ((kk & maskhi) == pfx)
                atomicAdd(&hist[(unsigned int)((kk >> shift) & 255ull)], 1u);
        }
        __syncthreads();
        unsigned int own = hist[tid];
        int val = (int)own;
        #pragma unroll
        for (int off = 1; off < 64; off <<= 1) {
            int n = __shfl_up(val, off);
            if (lane >= off) val += n;
        }
        if (lane == 63) wsum[wv] = (unsigned int)val;
        __syncthreads();
        unsigned int woff = 0;
        for (int q = 0; q < wv; ++q) woff += wsum[q];
        unsigned int incl = (unsigned int)val + woff;
        unsigned int excl = incl - own;
        if (own > 0 && plo >= excl && plo < incl) { selDigit = (unsigned int)tid; selBase = excl; }
        __syncthreads();
        pfx |= ((unsigned long long)selDigit << shift);
        plo -= selBase;
        __syncthreads();
    }

    #pragma unroll
    for (int r = 0; r < 8; ++r) {
        int t = tid + r * 256;
        if (keys[t] >= pfx) atomicAdd(&cnt[(j * 8 + b) * T_ + t], 1);
    }
}

// ============================================================
// Kernel C: finalize g = cnt/5, write g & g_sweep & rho_eff, row sums
// ============================================================
__launch_bounds__(256)
__global__ void k_gfin(const int* __restrict__ cnt, const float* __restrict__ attn,
                       float* __restrict__ out, double* __restrict__ sumeff,
                       double* __restrict__ sumatt, double* __restrict__ sumg)
{
    __shared__ double redA[4], redB[4], redC[4];
    const int j = blockIdx.x >> 3, b = blockIdx.x & 7;
    const int tid = threadIdx.x;
    double sg = 0.0, se = 0.0, sa = 0.0;
    for (int t = tid; t < T_; t += 256) {
        int c = cnt[(j * 8 + b) * T_ + t];
        float g  = (float)c / 5.0f;
        float av = attn[b * T_ + t];
        out[OUT_GSW + (j * 8 + b) * T_ + t] = g;
        if (j == 4) out[OUT_G + b * T_ + t] = g;
        sg += (double)g;
        se += (double)(av * g);
        sa += (double)av;
    }
    for (int m = 32; m; m >>= 1) { sg += __shfl_xor(sg, m); se += __shfl_xor(se, m); sa += __shfl_xor(sa, m); }
    if ((tid & 63) == 0) { redA[tid>>6] = sg; redB[tid>>6] = se; redC[tid>>6] = sa; }
    __syncthreads();
    if (tid == 0) {
        sg = redA[0]+redA[1]+redA[2]+redA[3];
        se = redB[0]+redB[1]+redB[2]+redB[3];
        sa = redC[0]+redC[1]+redC[2]+redC[3];
        sumg[j*8+b] = sg; sumeff[j*8+b] = se;
        if (j == 0) sumatt[b] = sa;
        out[OUT_RHOEFF + j*8 + b] = (float)sg / (float)sa;
    }
}

// ============================================================
// Kernel D: pooled weighted sums over tok = emb_table[ids] (512 blocks)
// ============================================================
__launch_bounds__(256)
__global__ void k_pool(const int* __restrict__ ids, const float* __restrict__ attn,
                       const float* __restrict__ out, const float* __restrict__ emb_table,
                       double* __restrict__ predw, double* __restrict__ fullw)
{
    __shared__ int   sid[128];
    __shared__ float sw[6][128];
    const int blk = blockIdx.x;
    const int b  = blk >> 6;            // 8
    const int dc = (blk >> 4) & 3;      // 4
    const int tc = blk & 15;            // 16
    const int tid = threadIdx.x;
    const int d = dc * 256 + tid;
    if (tid < 128) {
        int t = tc * 128 + tid;
        sid[tid] = ids[b * T_ + t];
        float av = attn[b * T_ + t];
        sw[0][tid] = av;
        #pragma unroll
        for (int j = 0; j < 5; ++j) {
            float g = out[OUT_GSW + (j * 8 + b) * T_ + t];
            sw[1 + j][tid] = av * g;
        }
    }
    __syncthreads();
    double acc[6] = {0,0,0,0,0,0};
    #pragma unroll 4
    for (int i = 0; i < 128; ++i) {
        float val = emb_table[(size_t)sid[i] * D_ + d];
        #pragma unroll
        for (int c = 0; c < 6; ++c) acc[c] += (double)(val * sw[c][i]);
    }
    atomicAdd(&fullw[b * D_ + d], acc[0]);
    #pragma unroll
    for (int j = 0; j < 5; ++j)
        atomicAdd(&predw[(j * 8 + b) * D_ + d], acc[1 + j]);
}

// ============================================================
// Kernel E: losses (5 blocks, one per rho) + finalize
// ============================================================
__launch_bounds__(256)
__global__ void k_loss(const double* __restrict__ predw, const double* __restrict__ fullw,
                       const double* __restrict__ sumeff, const double* __restrict__ sumatt,
                       float* __restrict__ out, double* __restrict__ lrws)
{
    __shared__ double red[4];
    const int j = blockIdx.x;
    const int tid = threadIdx.x;
    double p = 0.0;
    for (int i = tid; i < B_ * D_; i += 256) {
        int b = i >> 10;
        double dF = sumatt[b];        if (dF < 1e-6) dF = 1e-6;
        double dE = sumeff[j*8 + b];  if (dE < 1e-6) dE = 1e-6;
        double diff = predw[j * B_ * D_ + i] / dE - fullw[i] / dF;
        p += diff * diff;
    }
    for (int m = 32; m; m >>= 1) p += __shfl_xor(p, m);
    if ((tid & 63) == 0) red[tid >> 6] = p;
    __syncthreads();
    if (tid == 0) {
        double t = red[0] + red[1] + red[2] + red[3];
        float lr = (float)(t / (double)(B_ * D_));
        out[OUT_LOSS + j] = lr;
        lrws[j] = (double)lr;
    }
}

__launch_bounds__(64)
__global__ void k_lfin(const double* __restrict__ lrws, float* __restrict__ out)
{
    if (threadIdx.x == 0) {
        float srec = 0.0f;
        for (int j = 0; j < 5; ++j) srec += (float)lrws[j];
        out[OUT_RECON] = srec / 5.0f;
    }
}

extern "C" void kernel_launch(void* const* d_in, const int* in_sizes, int n_in,
                              void* d_out, int out_size, void* d_ws, size_t ws_size,
                              hipStream_t stream)
{
    const int*   ids  = (const int*)  d_in[0];
    const float* emb  = (const float*)d_in[1];
    const float* attn = (const float*)d_in[2];
    const float* ln_g = (const float*)d_in[3];
    const float* ln_b = (const float*)d_in[4];
    const float* W1   = (const float*)d_in[5];
    const float* b1   = (const float*)d_in[6];
    const float* W2   = (const float*)d_in[7];
    const float* b2   = (const float*)d_in[8];
    const float* et   = (const float*)d_in[9];
    float* out = (float*)d_out;
    char*  ws  = (char*)d_ws;

    double* scores = (double*)(ws + WS_SCORES);
    int*    cnt    = (int*)   (ws + WS_CNT);
    double* predw  = (double*)(ws + WS_PREDW);
    double* fullw  = (double*)(ws + WS_FULLW);
    double* sumeff = (double*)(ws + WS_SUMEFF);
    double* sumatt = (double*)(ws + WS_SUMATT);
    double* sumg   = (double*)(ws + WS_SUMG);
    double* lrws   = (double*)(ws + WS_LR);
    float2* stats  = (float2*)(ws + WS_STATS);
    unsigned short* w1thi = (unsigned short*)(ws + WS_W1THI);
    unsigned short* w1tlo = (unsigned short*)(ws + WS_W1TLO);
    unsigned short* ahi   = (unsigned short*)(ws + WS_AHI);
    unsigned short* alo   = (unsigned short*)(ws + WS_ALO);

    hipMemsetAsync(d_ws, 0, WS_ZERO_BYTES, stream);

    k_w1t<<<48*32, 256, 0, stream>>>(W1, w1thi, w1tlo);
    if (ws_size >= WS_FULL_END) {
        k_asplit<<<NTOK/64, 256, 0, stream>>>(emb, attn, ln_g, ln_b, ahi, alo);
        k_scores8<<<768, 512, 0, stream>>>(ahi, alo, w1thi, w1tlo, b1, W2, scores);
    } else {
        k_stats<<<NTOK/64, 256, 0, stream>>>(emb, attn, stats);
        k_scores_fb<<<1408, 256, 0, stream>>>(emb, ln_g, ln_b, stats, w1thi, w1tlo,
                                              b1, W2, scores);
    }
    k_topk<<<NRHO * NSAMP * B_, 256, 0, stream>>>(scores, attn, b2, cnt);
    k_gfin<<<NRHO * B_, 256, 0, stream>>>(cnt, attn, out, sumeff, sumatt, sumg);
    k_pool<<<512, 256, 0, stream>>>(ids, attn, out, et, predw, fullw);
    k_loss<<<NRHO, 256, 0, stream>>>(predw, fullw, sumeff, sumatt, out, lrws);
    k_lfin<<<1, 64, 0, stream>>>(lrws, out);
}